// Round 2
// baseline (447.245 us; speedup 1.0000x reference)
//
#include <hip/hip_runtime.h>
#include <utility>

typedef unsigned int  u32;
typedef unsigned short u16;

// ======================= compile-time real-CG generation =======================
// Mirrors the Python reference exactly: _cg (Clebsch-Gordan), _u (real<-complex
// SH change of basis), _real_cg (einsum + pick R or I by abs-sum), all in double.

struct CEnt { int i, j, k; double c; };
struct PathTab { int n; CEnt e[400]; };
struct cxd { double re, im; };
struct URow { int n; int col[2]; cxd v[2]; };

constexpr double FT[14] = {1.,1.,2.,6.,24.,120.,720.,5040.,40320.,362880.,
                           3628800.,39916800.,479001600.,6227020800.};

constexpr double cabs_(double x){ return x < 0 ? -x : x; }

constexpr double csqrt_(double x){
  if (x <= 0.) return 0.;
  double g = 1.;
  while (g*g < x) g *= 2.;
  for (int it = 0; it < 50; ++it) g = 0.5*(g + x/g);
  return g;
}

constexpr double cg_(int j1,int m1,int j2,int m2,int j3,int m3){
  if (m1 + m2 != m3) return 0.;
  int dj = j1 - j2; if (dj < 0) dj = -dj;
  if (j3 < dj || j3 > j1 + j2) return 0.;
  double preA = (double)(2*j3+1)*FT[j3+j1-j2]*FT[j3-j1+j2]*FT[j1+j2-j3]/FT[j1+j2+j3+1];
  double preB = FT[j3+m3]*FT[j3-m3]*FT[j1-m1]*FT[j1+m1]*FT[j2-m2]*FT[j2+m2];
  double pre = csqrt_(preA)*csqrt_(preB);
  int kmin = 0;
  if (j2-j3-m1 > kmin) kmin = j2-j3-m1;
  if (j1-j3+m2 > kmin) kmin = j1-j3+m2;
  int kmax = j1+j2-j3;
  if (j1-m1 < kmax) kmax = j1-m1;
  if (j2+m2 < kmax) kmax = j2+m2;
  double s = 0.;
  for (int k = kmin; k <= kmax; ++k){
    double d = FT[k]*FT[j1+j2-j3-k]*FT[j1-m1-k]*FT[j2+m2-k]*FT[j3-j2+m1+k]*FT[j3-j1-m2+k];
    s += ((k & 1) ? -1.0 : 1.0)/d;
  }
  return pre*s;
}

constexpr URow urow_(int l, int r){
  URow R{};
  const double s2 = 0.7071067811865476; // 2**-0.5
  int m = r - l;
  if (m == 0){ R.n = 1; R.col[0] = l; R.v[0] = {1., 0.}; }
  else if (m > 0){
    R.n = 2;
    R.col[0] = l + m; R.v[0] = { (m & 1) ? -s2 : s2, 0. };   // U[l+m,l+m] = (-1)^m/sqrt2
    R.col[1] = l - m; R.v[1] = { s2, 0. };                    // U[l+m,l-m] = 1/sqrt2
  } else {
    int mm = -m;
    R.n = 2;
    R.col[0] = l - mm; R.v[0] = { 0., s2 };                   // U[l-m,l-m] = i/sqrt2
    R.col[1] = l + mm; R.v[1] = { 0., (mm & 1) ? s2 : -s2 };  // U[l-m,l+m] = -i(-1)^m/sqrt2
  }
  return R;
}

constexpr cxd cmul_(cxd a, cxd b){ return { a.re*b.re - a.im*b.im, a.re*b.im + a.im*b.re }; }

constexpr PathTab buildPath(int l1, int l2, int l3){
  const int n1 = 2*l1+1, n2 = 2*l2+1, n3 = 2*l3+1;
  double cgd[9][9][9] = {};
  for (int a = 0; a < n1; ++a)
    for (int b = 0; b < n2; ++b)
      for (int c = 0; c < n3; ++c)
        cgd[a][b][c] = cg_(l1, a-l1, l2, b-l2, l3, c-l3);

  double MR[9][9][9] = {}; double MI[9][9][9] = {};
  double sR = 0., sI = 0.;
  for (int i = 0; i < n1; ++i){
    URow u1 = urow_(l1, i);
    for (int j = 0; j < n2; ++j){
      URow u2 = urow_(l2, j);
      for (int k = 0; k < n3; ++k){
        URow u3 = urow_(l3, k);
        double mre = 0., mim = 0.;
        for (int a = 0; a < u1.n; ++a)
          for (int b = 0; b < u2.n; ++b)
            for (int c = 0; c < u3.n; ++c){
              double cv = cgd[u1.col[a]][u2.col[b]][u3.col[c]];
              if (cv != 0.){
                cxd t = cmul_(u1.v[a], u2.v[b]);
                cxd u3c = { u3.v[c].re, -u3.v[c].im };         // conj(U3)
                t = cmul_(t, u3c);
                mre += t.re*cv; mim += t.im*cv;
              }
            }
        MR[i][j][k] = mre; MI[i][j][k] = mim;
        sR += cabs_(mre); sI += cabs_(mim);
      }
    }
  }
  const bool useR = (sR >= sI);

  PathTab P{}; P.n = 0;
  if (l1 == l2){
    // y1 == y2 in both stages: merge (i,j) with (j,i) exactly.
    for (int i = 0; i < n1; ++i)
      for (int j = i; j < n2; ++j)
        for (int k = 0; k < n3; ++k){
          double v = useR ? MR[i][j][k] : MI[i][j][k];
          if (j > i) v += useR ? MR[j][i][k] : MI[j][i][k];
          if (cabs_(v) > 1e-12){
            if (P.n >= 400) { P.n = -1; return P; }
            P.e[P.n].i = i; P.e[P.n].j = j; P.e[P.n].k = k; P.e[P.n].c = v; P.n++;
          }
        }
  } else {
    for (int i = 0; i < n1; ++i)
      for (int j = 0; j < n2; ++j)
        for (int k = 0; k < n3; ++k){
          double v = useR ? MR[i][j][k] : MI[i][j][k];
          if (cabs_(v) > 1e-12){
            if (P.n >= 400) { P.n = -1; return P; }
            P.e[P.n].i = i; P.e[P.n].j = j; P.e[P.n].k = k; P.e[P.n].c = v; P.n++;
          }
        }
  }
  return P;
}

template<int L1,int L2,int L3>
struct CGT { static constexpr PathTab t = buildPath(L1, L2, L3); };

// ======================= unrolled sparse contraction =======================
// Association c * (w * (yi*yj)) lets the compiler CSE (w*(yi*yj)) across the
// multiple k entries sharing one (i,j) pair.

template<int L1,int L2,int L3,int... S>
__device__ __forceinline__ void apply_one_(const float* __restrict__ y,
                                           float* __restrict__ o,
                                           float wpf,
                                           std::integer_sequence<int, S...>){
  (( o[L3*L3 + CGT<L1,L2,L3>::t.e[S].k] +=
       (float)CGT<L1,L2,L3>::t.e[S].c
       * (wpf * (y[L1*L1 + CGT<L1,L2,L3>::t.e[S].i] * y[L2*L2 + CGT<L1,L2,L3>::t.e[S].j])) ), ...);
}

template<int L1,int L2,int L3>
__device__ __forceinline__ void apply_path_(const float* __restrict__ y,
                                            float* __restrict__ o, float wpf){
  apply_one_<L1,L2,L3>(y, o, wpf,
      std::make_integer_sequence<int, CGT<L1,L2,L3>::t.n>{});
}

// Path lists in the reference's exact enumeration order (weight index order).
#define PL1(X) X(0,0,0) X(0,1,1) X(0,2,2) X(0,3,3) \
  X(1,0,1) X(1,1,0) X(1,1,1) X(1,1,2) X(1,2,1) X(1,2,2) X(1,2,3) X(1,3,2) X(1,3,3) X(1,3,4) \
  X(2,0,2) X(2,1,1) X(2,1,2) X(2,1,3) X(2,2,0) X(2,2,1) X(2,2,2) X(2,2,3) X(2,2,4) \
  X(2,3,1) X(2,3,2) X(2,3,3) X(2,3,4) \
  X(3,0,3) X(3,1,2) X(3,1,3) X(3,1,4) X(3,2,1) X(3,2,2) X(3,2,3) X(3,2,4) \
  X(3,3,0) X(3,3,1) X(3,3,2) X(3,3,3) X(3,3,4)

#define PL2(X) X(0,0,0) X(0,1,1) X(0,2,2) X(0,3,3) X(0,4,4) \
  X(1,0,1) X(1,1,0) X(1,1,1) X(1,1,2) X(1,2,1) X(1,2,2) X(1,2,3) X(1,3,2) X(1,3,3) X(1,3,4) X(1,4,3) X(1,4,4) \
  X(2,0,2) X(2,1,1) X(2,1,2) X(2,1,3) X(2,2,0) X(2,2,1) X(2,2,2) X(2,2,3) X(2,2,4) \
  X(2,3,1) X(2,3,2) X(2,3,3) X(2,3,4) X(2,4,2) X(2,4,3) X(2,4,4) \
  X(3,0,3) X(3,1,2) X(3,1,3) X(3,1,4) X(3,2,1) X(3,2,2) X(3,2,3) X(3,2,4) \
  X(3,3,0) X(3,3,1) X(3,3,2) X(3,3,3) X(3,3,4) X(3,4,1) X(3,4,2) X(3,4,3) X(3,4,4) \
  X(4,0,4) X(4,1,3) X(4,1,4) X(4,2,2) X(4,2,3) X(4,2,4) X(4,3,1) X(4,3,2) X(4,3,3) X(4,3,4) \
  X(4,4,0) X(4,4,1) X(4,4,2) X(4,4,3) X(4,4,4)

// ======================= main kernel =======================
// thread = (edge, radial f). block = 16 edges x 16 f. Output staged in LDS as
// f32 then stored fully coalesced.

__global__ __launch_bounds__(256) void acmd_kernel(
    const float* __restrict__ disp,
    const float* __restrict__ w1g,
    const float* __restrict__ w2g,
    float* __restrict__ outf, int E)
{
  __shared__ float w1s[40*16];
  __shared__ float w2s[65*16];
  __shared__ float tilef[6400];   // 16 edges * 400 f32 = 25.6 KB

  for (int i = threadIdx.x; i < 40*16; i += 256) w1s[i] = w1g[i];
  for (int i = threadIdx.x; i < 65*16; i += 256) w2s[i] = w2g[i];
  __syncthreads();

  const int le = threadIdx.x >> 4;     // local edge 0..15
  const int f  = threadIdx.x & 15;     // radial channel 0..15
  const int e  = blockIdx.x*16 + le;

  float out[25];
#pragma unroll
  for (int k = 0; k < 25; ++k) out[k] = 0.f;

  if (e < E){
    const float dx = disp[3*e+0], dy = disp[3*e+1], dz = disp[3*e+2];
    const float r  = sqrtf(dx*dx + dy*dy + dz*dz);
    const float x  = r * (1.0f/5.0f);                 // r / CUTOFF
    const float inv = 1.0f / fmaxf(r, 1e-9f);
    const float ux = dx*inv, uy = dy*inv, uz = dz*inv;

    // cut = x<1 ? exp(1 - 1/(1-x^2)) : 0
    const float cut = (x < 1.0f) ? expf(1.0f - 1.0f/(1.0f - x*x)) : 0.0f;

    const float sx2 = ux*ux, sy2 = uy*uy, sz2 = uz*uz;
    float shp[16];
    shp[0]  = 0.28209479177387814f;
    shp[1]  = 0.4886025119029199f*uy;
    shp[2]  = 0.4886025119029199f*uz;
    shp[3]  = 0.4886025119029199f*ux;
    shp[4]  = 1.0925484305920792f*ux*uy;
    shp[5]  = 1.0925484305920792f*uy*uz;
    shp[6]  = 0.31539156525252005f*(3.0f*sz2 - 1.0f);
    shp[7]  = 1.0925484305920792f*ux*uz;
    shp[8]  = 0.5462742152960396f*(sx2 - sy2);
    shp[9]  = 0.5900435899266435f*uy*(3.0f*sx2 - sy2);
    shp[10] = 2.890611442640554f*ux*uy*uz;
    shp[11] = 0.4570457994644658f*uy*(5.0f*sz2 - 1.0f);
    shp[12] = 0.3731763325901154f*uz*(5.0f*sz2 - 3.0f);
    shp[13] = 0.4570457994644658f*ux*(5.0f*sz2 - 1.0f);
    shp[14] = 1.445305721320277f*uz*(sx2 - sy2);
    shp[15] = 0.5900435899266435f*ux*(sx2 - 3.0f*sy2);
#pragma unroll
    for (int i = 0; i < 16; ++i) shp[i] *= cut;

    // this thread's radial basis value: sinc(x*(f+1)) (normalized sinc)
    const float tt = x * (float)(f + 1);
    const float pt = 3.14159265358979f * tt;
    const float rb = (pt > 1e-5f) ? (sinf(pt)/pt) : (1.0f - pt*pt*(1.0f/6.0f));
    const float rb2 = rb*rb;

    // stage 1: z1[k] = rb^2 * sum_p w1[p,f] * sum_{ij} C_p[i,j,k] shp_i shp_j
    float z1[25];
#pragma unroll
    for (int k = 0; k < 25; ++k) z1[k] = 0.f;
    {
      int pp = 0;
#define AP1(a,b,c) apply_path_<a,b,c>(shp, z1, w1s[(pp++)*16 + f]);
      PL1(AP1)
#undef AP1
    }
#pragma unroll
    for (int k = 0; k < 25; ++k) z1[k] *= rb2;

    // stage 2: out[k] = sum_p w2[p,f] * sum_{ij} C_p[i,j,k] z1_i z1_j
    {
      int qq = 0;
#define AP2(a,b,c) apply_path_<a,b,c>(z1, out, w2s[(qq++)*16 + f]);
      PL2(AP2)
#undef AP2
    }
  }

  // stage f32 output tile in LDS, then coalesced store
#pragma unroll
  for (int k = 0; k < 25; ++k)
    tilef[le*400 + k*16 + f] = out[k];
  __syncthreads();

  const long long base  = (long long)blockIdx.x * 6400;  // f32 elements
  const long long total = (long long)E * 400;
  if (base + 6400 <= total){
    float* dst = outf + base;
    for (int i = threadIdx.x; i < 6400; i += 256) dst[i] = tilef[i];
  } else {
    for (int i = threadIdx.x; i < 6400 && base + i < total; i += 256) outf[base + i] = tilef[i];
  }
}

// ======================= launch =======================

extern "C" void kernel_launch(void* const* d_in, const int* in_sizes, int n_in,
                              void* d_out, int out_size, void* d_ws, size_t ws_size,
                              hipStream_t stream){
  const float* disp = (const float*)d_in[1];   // neighbour_displacements (E,3) f32
  const float* w1   = (const float*)d_in[3];   // tp_weights1 (40,16) f32
  const float* w2   = (const float*)d_in[4];   // tp_weights2 (65,16) f32
  const int E = in_sizes[1] / 3;
  const int blocks = (E + 15) / 16;
  acmd_kernel<<<blocks, 256, 0, stream>>>(disp, w1, w2, (float*)d_out, E);
}